// Round 1
// baseline (1367.097 us; speedup 1.0000x reference)
//
#include <hip/hip_runtime.h>
#include <cstdint>
#include <cstddef>

#define B_ 8
#define C_ 32
#define W_ 32
#define H_ 32
#define A_ 6
#define NCLS 14
#define M_ 64
#define HARD_NUM 256
#define LAM_HNM 0.2f
#define LAM_NOOBJ 0.001f

#define NCH 17                       // 3 + NCLS
#define NPOS (B_*C_*W_*H_*A_)        // 1,572,864 values per class
#define TOTAL (NPOS*NCH)             // 26,738,688 floats
#define NBINS 32768
#define BIN_SHIFT 17                 // key >> 17 -> 15-bit bin

// ws layout: [ uint64 hist[NCLS*NBINS] ][ float facc[8] ][ uint uacc[24] ]
// facc: 0=cl_pos 1=cl_neg 2=reg 3=regu 4=hn_sum
// uacc: 0=pos_count, 1..14 = per-class hn counts

__device__ __forceinline__ float softplus_f(float x) {
    return fmaxf(x, 0.0f) + log1pf(__expf(-fabsf(x)));
}

__global__ void k1_hist(const float* __restrict__ pm,
                        unsigned long long* __restrict__ hist,
                        float* __restrict__ facc) {
    const int tid = blockIdx.x * blockDim.x + threadIdx.x;
    const int nth = gridDim.x * blockDim.x;
    const int n4 = TOTAL / 4;
    float racc = 0.0f;
    for (int i = tid; i < n4; i += nth) {
        float4 v = reinterpret_cast<const float4*>(pm)[i];
        float vv[4] = {v.x, v.y, v.z, v.w};
        int base = i * 4;
#pragma unroll
        for (int j = 0; j < 4; ++j) {
            float x = vv[j];
            int idx = base + j;
            int ch = idx % NCH;
            float s = softplus_f(x);
            racc += s;
            if (ch >= 3) {
                unsigned u = __float_as_uint(x);
                unsigned key = (u & 0x80000000u) ? ~u : (u | 0x80000000u);
                unsigned bin = key >> BIN_SHIFT;
                int cls = ch - 3;
                unsigned long long pk =
                    (1ull << 44) | (unsigned long long)(s * 1048576.0f + 0.5f);
                atomicAdd(&hist[(size_t)cls * NBINS + bin], pk);
            }
        }
    }
    // block reduction of regu partial
    for (int off = 32; off; off >>= 1) racc += __shfl_down(racc, off, 64);
    __shared__ float wsum[4];
    int lane = threadIdx.x & 63, wid = threadIdx.x >> 6;
    if (lane == 0) wsum[wid] = racc;
    __syncthreads();
    if (threadIdx.x == 0) {
        float ssum = wsum[0] + wsum[1] + wsum[2] + wsum[3];
        atomicAdd(&facc[3], ssum);
    }
}

__global__ void k2_props(const float* __restrict__ pm,
                         const int* __restrict__ pidx,
                         const float* __restrict__ preg,
                         float* __restrict__ facc,
                         unsigned* __restrict__ uacc) {
    int t = blockIdx.x * blockDim.x + threadIdx.x;
    if (t >= B_ * A_ * M_) return;
    int b = t / (A_ * M_);
    int a = (t / M_) % A_;
    const int* q = pidx + (size_t)t * 4;
    int c = q[0], w = q[1], h = q[2], lab = q[3];
    if (lab == -100) return;
    if (lab < 0) {
        int j = -1 - lab;                  // hard-negative class
        atomicAdd(&uacc[1 + j], 1u);
        return;
    }
    atomicAdd(&uacc[0], 1u);               // positive count
    const float* v = pm + (size_t)((((b * C_ + c) * W_ + w) * H_ + h) * A_ + a) * NCH;
    float clp = 0.0f, cln = 0.0f;
#pragma unroll
    for (int j = 0; j < NCLS; ++j) {
        float lg = v[3 + j];
        if (j == lab) clp = softplus_f(-lg);
        else          cln += softplus_f(lg);
    }
    float rg = 0.0f;
    const float* pr = preg + (size_t)t * 3;
#pragma unroll
    for (int j = 0; j < 3; ++j) {
        float d = tanhf(v[j]) - pr[j];
        float ad = fabsf(d);
        rg += (ad < 1.0f) ? 0.5f * d * d : ad - 0.5f;
    }
    atomicAdd(&facc[0], clp);
    atomicAdd(&facc[1], cln);
    atomicAdd(&facc[2], rg);
}

__global__ void k3_select(const unsigned long long* __restrict__ hist,
                          const unsigned* __restrict__ uacc,
                          float* __restrict__ facc) {
    int cls = blockIdx.x;
    unsigned k = uacc[1 + cls] * HARD_NUM;
    if (k == 0) return;                      // uniform across block
    __shared__ unsigned ccnt[256];
    __shared__ float    csum[256];
    __shared__ unsigned bc[128];
    __shared__ float    bs[128];
    __shared__ int      sel_chunk;
    __shared__ unsigned cum_before;
    __shared__ float    s_above;
    int t = threadIdx.x;
    const unsigned long long* hc = hist + (size_t)cls * NBINS;
    unsigned lc = 0; float ls = 0.0f;
    for (int i = 0; i < 128; ++i) {
        unsigned long long v = hc[t * 128 + i];
        lc += (unsigned)(v >> 44);
        ls += (float)(v & ((1ull << 44) - 1)) * (1.0f / 1048576.0f);
    }
    ccnt[t] = lc; csum[t] = ls;
    __syncthreads();
    if (t == 0) {
        unsigned cum = 0; float sa = 0.0f; int sc = -1;
        for (int ch = 255; ch >= 0; --ch) {
            if (cum + ccnt[ch] >= k) { sc = ch; break; }
            cum += ccnt[ch]; sa += csum[ch];
        }
        sel_chunk = sc;
        cum_before = cum;
        s_above = sa;
        if (sc < 0) atomicAdd(&facc[4], sa);   // k >= total (won't happen)
    }
    __syncthreads();
    int sc = sel_chunk;
    if (sc < 0) return;
    if (t < 128) {
        unsigned long long v = hc[sc * 128 + t];
        bc[t] = (unsigned)(v >> 44);
        bs[t] = (float)(v & ((1ull << 44) - 1)) * (1.0f / 1048576.0f);
    }
    __syncthreads();
    if (t == 0) {
        unsigned cum = cum_before; float sa = s_above;
        for (int i = 127; i >= 0; --i) {
            if (cum + bc[i] >= k) {
                unsigned r = k - cum;          // >=1, bc[i] >= 1 here
                sa += (float)r * (bs[i] / (float)bc[i]);
                atomicAdd(&facc[4], sa);
                break;
            }
            cum += bc[i]; sa += bs[i];
        }
    }
}

__global__ void k4_final(const float* __restrict__ facc,
                         const unsigned* __restrict__ uacc,
                         float* __restrict__ out) {
    float P = fmaxf((float)uacc[0], 1.0f);
    unsigned totk = 0;
    for (int j = 0; j < NCLS; ++j) totk += uacc[1 + j];
    totk *= HARD_NUM;
    float hn = (totk > 0) ? (LAM_HNM * facc[4] / (float)totk) : 0.0f;
    float res = facc[0] / P
              + facc[1] / (P * (float)((NCLS - 1) * (NCLS - 1)))
              + hn
              + LAM_NOOBJ * facc[3] / (float)TOTAL
              + facc[2] / (3.0f * P);
    out[0] = res;
}

extern "C" void kernel_launch(void* const* d_in, const int* in_sizes, int n_in,
                              void* d_out, int out_size, void* d_ws, size_t ws_size,
                              hipStream_t stream) {
    const float* pm   = (const float*)d_in[0];
    const int*   pidx = (const int*)d_in[1];
    const float* preg = (const float*)d_in[2];
    float* out = (float*)d_out;

    unsigned long long* hist = (unsigned long long*)d_ws;
    const size_t HIST_BYTES = (size_t)NCLS * NBINS * 8;
    float*    facc = (float*)((char*)d_ws + HIST_BYTES);
    unsigned* uacc = (unsigned*)(facc + 8);

    hipMemsetAsync(d_ws, 0, HIST_BYTES + 128, stream);
    k1_hist  <<<2048, 256, 0, stream>>>(pm, hist, facc);
    k2_props <<<(B_*A_*M_ + 255) / 256, 256, 0, stream>>>(pm, pidx, preg, facc, uacc);
    k3_select<<<NCLS, 256, 0, stream>>>(hist, uacc, facc);
    k4_final <<<1, 1, 0, stream>>>(facc, uacc, out);
}

// Round 3
// 194.590 us; speedup vs baseline: 7.0255x; 7.0255x over previous
//
#include <hip/hip_runtime.h>
#include <cstdint>
#include <cstddef>

#define B_ 8
#define C_ 32
#define W_ 32
#define H_ 32
#define A_ 6
#define NCLS 14
#define M_ 64
#define HARD_NUM 256
#define LAM_HNM 0.2f
#define LAM_NOOBJ 0.001f

#define NCH 17
#define NPOS (B_*C_*W_*H_*A_)
#define TOTAL (NPOS*NCH)          // 26,738,688 floats

#define ABITS 11
#define NBIN_C (1<<ABITS)         // 2048 coarse bins
#define PAIRS 7                   // 14 classes packed 2 per u32 (u16 halves)
#define HSLOTS (NBIN_C*PAIRS)     // 14336
#define SUBBITS 11
#define NBIN_F (1<<SUBBITS)       // 2048 fine sub-bins

// ws layout
#define OFF_FACC   0              // float[16]: 0=cl_pos 1=cl_neg 2=reg 3=regu 4=hn_sum
#define OFF_UACC   64             // u32[16]:  0=pos_count, 1..14=per-class hn counts
#define OFF_BSTAR  128            // i32[16]
#define OFF_CNTAB  192            // u32[16]
#define OFF_SUMAB  256            // f32[16]
#define OFF_MERGED 4096           // u32[NBIN_C*14] = 114688 B
#define OFF_FINE   (4096+114688)  // u64[NCLS*NBIN_F] = 229376 B
#define OFF_PART   (OFF_FINE+229376)   // 348160, partials follow
#define FIXED_BYTES OFF_PART

__device__ __forceinline__ float sp(float x) {
    return fmaxf(x, 0.0f) + log1pf(__expf(-fabsf(x)));
}

__device__ __forceinline__ unsigned fkey(float x) {
    unsigned u = __float_as_uint(x);
    return (u & 0x80000000u) ? ~u : (u | 0x80000000u);
}

// ---------------- pass A: coarse per-class LDS histogram + regu sum ----------
__global__ __launch_bounds__(1024) void ka_coarse(const float* __restrict__ pm,
                                                  unsigned* __restrict__ partials,
                                                  float* __restrict__ facc) {
    __shared__ unsigned hist[HSLOTS];
    for (int i = threadIdx.x; i < HSLOTS; i += blockDim.x) hist[i] = 0;
    __syncthreads();
    int tid = blockIdx.x * blockDim.x + threadIdx.x;
    int nth = gridDim.x * blockDim.x;
    float racc = 0.0f;
    for (int i = tid; i < TOTAL / 4; i += nth) {
        float4 v = reinterpret_cast<const float4*>(pm)[i];
        int base = i * 4;
        int ch = base % NCH;
        float vv[4] = {v.x, v.y, v.z, v.w};
#pragma unroll
        for (int j = 0; j < 4; ++j) {
            float x = vv[j];
            float s = sp(x);
            racc += s;
            if (ch >= 3) {
                int cls = ch - 3;
                unsigned bin = fkey(x) >> (32 - ABITS);
                atomicAdd(&hist[bin * PAIRS + (cls >> 1)],
                          (cls & 1) ? 0x10000u : 1u);
            }
            ch = (ch == NCH - 1) ? 0 : ch + 1;
        }
    }
    __syncthreads();
    unsigned* dst = partials + (size_t)blockIdx.x * HSLOTS;
    for (int i = threadIdx.x; i < HSLOTS; i += blockDim.x) dst[i] = hist[i];
    for (int off = 32; off; off >>= 1) racc += __shfl_down(racc, off, 64);
    __shared__ float wsum[16];
    int lane = threadIdx.x & 63, wid = threadIdx.x >> 6;
    if (lane == 0) wsum[wid] = racc;
    __syncthreads();
    if (threadIdx.x == 0) {
        float ssum = 0.0f;
        int nw = blockDim.x >> 6;
        for (int w = 0; w < nw; ++w) ssum += wsum[w];
        atomicAdd(&facc[3], ssum);
    }
}

// ---------------- reduce partials -> merged coarse hist ----------------------
__global__ void kr_reduce(const unsigned* __restrict__ partials,
                          unsigned* __restrict__ merged, int nparts) {
    int e = blockIdx.x * blockDim.x + threadIdx.x;
    if (e >= HSLOTS) return;
    unsigned a0 = 0, a1 = 0;
#pragma unroll 4
    for (int p = 0; p < nparts; ++p) {
        unsigned v = partials[(size_t)p * HSLOTS + e];
        a0 += v & 0xFFFFu;
        a1 += v >> 16;
    }
    int bin = e / PAIRS, pair = e % PAIRS;
    merged[bin * 14 + 2 * pair] = a0;
    merged[bin * 14 + 2 * pair + 1] = a1;
}

// ---------------- proposals: pos losses + hn counts --------------------------
__global__ void k2_props(const float* __restrict__ pm,
                         const int* __restrict__ pidx,
                         const float* __restrict__ preg,
                         float* __restrict__ facc,
                         unsigned* __restrict__ uacc) {
    int t = blockIdx.x * blockDim.x + threadIdx.x;
    if (t >= B_ * A_ * M_) return;
    int b = t / (A_ * M_);
    int a = (t / M_) % A_;
    const int* q = pidx + (size_t)t * 4;
    int c = q[0], w = q[1], h = q[2], lab = q[3];
    if (lab == -100) return;
    if (lab < 0) {
        atomicAdd(&uacc[1 + (-1 - lab)], 1u);
        return;
    }
    atomicAdd(&uacc[0], 1u);
    const float* v = pm + (size_t)((((b * C_ + c) * W_ + w) * H_ + h) * A_ + a) * NCH;
    float clp = 0.0f, cln = 0.0f;
#pragma unroll
    for (int j = 0; j < NCLS; ++j) {
        float lg = v[3 + j];
        if (j == lab) clp = sp(-lg);
        else          cln += sp(lg);
    }
    float rg = 0.0f;
    const float* pr = preg + (size_t)t * 3;
#pragma unroll
    for (int j = 0; j < 3; ++j) {
        float d = tanhf(v[j]) - pr[j];
        float ad = fabsf(d);
        rg += (ad < 1.0f) ? 0.5f * d * d : ad - 0.5f;
    }
    atomicAdd(&facc[0], clp);
    atomicAdd(&facc[1], cln);
    atomicAdd(&facc[2], rg);
}

// ---------------- per-class coarse boundary find -----------------------------
__global__ void kb_boundary(const unsigned* __restrict__ merged,
                            const unsigned* __restrict__ uacc,
                            int* __restrict__ bstar,
                            unsigned* __restrict__ cntab) {
    int cls = blockIdx.x, t = threadIdx.x;
    unsigned k = uacc[1 + cls] * HARD_NUM;
    if (k == 0) { if (t == 0) bstar[cls] = -2; return; }
    __shared__ unsigned ck[256];
    const int CPB = NBIN_C / 256;      // 8 bins per chunk
    unsigned lc = 0;
    for (int j = 0; j < CPB; ++j) lc += merged[(t * CPB + j) * 14 + cls];
    ck[t] = lc;
    __syncthreads();
    if (t == 0) {
        unsigned cum = 0; int sc = -1;
        for (int ch = 255; ch >= 0; --ch) {
            if (cum + ck[ch] >= k) { sc = ch; break; }
            cum += ck[ch];
        }
        if (sc < 0) { bstar[cls] = -1; cntab[cls] = cum; return; }
        for (int j = CPB - 1; j >= 0; --j) {
            int bin = sc * CPB + j;
            unsigned c = merged[bin * 14 + cls];
            if (cum + c >= k) { bstar[cls] = bin; cntab[cls] = cum; return; }
            cum += c;
        }
    }
}

// ---------------- pass B: sum above boundary + fine hist of boundary bin -----
__global__ void kb_pass(const float* __restrict__ pm,
                        const int* __restrict__ bstar,
                        unsigned long long* __restrict__ fine,
                        float* __restrict__ sumab) {
    __shared__ float csum[16];
    __shared__ int bst[16];
    int t = threadIdx.x;
    if (t < 16) { csum[t] = 0.0f; bst[t] = (t < 14) ? bstar[t] : -2; }
    __syncthreads();
    int tid = blockIdx.x * blockDim.x + t;
    int nth = gridDim.x * blockDim.x;
    for (int i = tid; i < TOTAL / 4; i += nth) {
        float4 v = reinterpret_cast<const float4*>(pm)[i];
        int base = i * 4;
        int ch = base % NCH;
        float vv[4] = {v.x, v.y, v.z, v.w};
#pragma unroll
        for (int j = 0; j < 4; ++j) {
            if (ch >= 3) {
                int cls = ch - 3;
                int b = bst[cls];
                if (b != -2) {
                    float x = vv[j];
                    unsigned key = fkey(x);
                    int bin = key >> (32 - ABITS);
                    if (bin > b) {
                        atomicAdd(&csum[cls], sp(x));
                    } else if (bin == b) {
                        unsigned sub = (key >> (32 - ABITS - SUBBITS)) & (NBIN_F - 1);
                        unsigned long long pk =
                            (1ull << 43) |
                            (unsigned long long)(sp(x) * 262144.0f + 0.5f);
                        atomicAdd(&fine[(size_t)cls * NBIN_F + sub], pk);
                    }
                }
            }
            ch = (ch == NCH - 1) ? 0 : ch + 1;
        }
    }
    __syncthreads();
    if (t < 14 && csum[t] != 0.0f) atomicAdd(&sumab[t], csum[t]);
}

// ---------------- resolve fine hist -> hn sum --------------------------------
__global__ void kc_resolve(const unsigned long long* __restrict__ fine,
                           const unsigned* __restrict__ uacc,
                           const int* __restrict__ bstar,
                           const unsigned* __restrict__ cntab,
                           const float* __restrict__ sumab,
                           float* __restrict__ facc) {
    int cls = blockIdx.x, t = threadIdx.x;
    unsigned k = uacc[1 + cls] * HARD_NUM;
    if (k == 0) return;
    int b = bstar[cls];
    if (b == -1) {
        if (t == 0) atomicAdd(&facc[4], sumab[cls]);
        return;
    }
    unsigned r = k - cntab[cls];      // >= 1 by construction
    const unsigned long long* fc = fine + (size_t)cls * NBIN_F;
    const int CPB = NBIN_F / 256;     // 8
    __shared__ unsigned ck[256];
    __shared__ float cs[256];
    unsigned lc = 0; float ls = 0.0f;
    for (int j = 0; j < CPB; ++j) {
        unsigned long long v = fc[t * CPB + j];
        lc += (unsigned)(v >> 43);
        ls += (float)(v & ((1ull << 43) - 1)) * (1.0f / 262144.0f);
    }
    ck[t] = lc; cs[t] = ls;
    __syncthreads();
    if (t == 0) {
        unsigned cum = 0; float sa = sumab[cls];
        for (int ch = 255; ch >= 0; --ch) {
            if (cum + ck[ch] >= r) {
                unsigned c2 = cum;
                for (int j = CPB - 1; j >= 0; --j) {
                    unsigned long long v = fc[ch * CPB + j];
                    unsigned c = (unsigned)(v >> 43);
                    float s = (float)(v & ((1ull << 43) - 1)) * (1.0f / 262144.0f);
                    if (c2 + c >= r) {
                        unsigned rem = r - c2;
                        if (c > 0) sa += (float)rem * (s / (float)c);
                        break;
                    }
                    c2 += c; sa += s;
                }
                break;
            }
            cum += ck[ch]; sa += cs[ch];
        }
        atomicAdd(&facc[4], sa);
    }
}

// ---------------- final combine ----------------------------------------------
__global__ void k4_final(const float* __restrict__ facc,
                         const unsigned* __restrict__ uacc,
                         float* __restrict__ out) {
    float P = fmaxf((float)uacc[0], 1.0f);
    unsigned totk = 0;
    for (int j = 0; j < NCLS; ++j) totk += uacc[1 + j];
    totk *= HARD_NUM;
    float hn = (totk > 0) ? (LAM_HNM * facc[4] / (float)totk) : 0.0f;
    out[0] = facc[0] / P
           + facc[1] / (P * (float)((NCLS - 1) * (NCLS - 1)))
           + hn
           + LAM_NOOBJ * facc[3] / (float)TOTAL
           + facc[2] / (3.0f * P);
}

extern "C" void kernel_launch(void* const* d_in, const int* in_sizes, int n_in,
                              void* d_out, int out_size, void* d_ws, size_t ws_size,
                              hipStream_t stream) {
    const float* pm   = (const float*)d_in[0];
    const int*   pidx = (const int*)d_in[1];
    const float* preg = (const float*)d_in[2];
    float* out = (float*)d_out;
    char* ws = (char*)d_ws;

    float*    facc  = (float*)(ws + OFF_FACC);
    unsigned* uacc  = (unsigned*)(ws + OFF_UACC);
    int*      bstar = (int*)(ws + OFF_BSTAR);
    unsigned* cntab = (unsigned*)(ws + OFF_CNTAB);
    float*    sumab = (float*)(ws + OFF_SUMAB);
    unsigned* merged = (unsigned*)(ws + OFF_MERGED);
    unsigned long long* fine = (unsigned long long*)(ws + OFF_FINE);
    unsigned* partials = (unsigned*)(ws + OFF_PART);

    size_t avail = (ws_size > (size_t)FIXED_BYTES)
                 ? (ws_size - FIXED_BYTES) / (HSLOTS * 4) : 0;
    int nparts = (avail < 256) ? (int)avail : 256;
    if (nparts < 32) nparts = 32;   // u16 packing safe down to 32 parts

    (void)hipMemsetAsync(ws, 0, FIXED_BYTES, stream);
    k2_props  <<<(B_*A_*M_ + 255) / 256, 256, 0, stream>>>(pm, pidx, preg, facc, uacc);
    ka_coarse <<<nparts, 1024, 0, stream>>>(pm, partials, facc);
    kr_reduce <<<(HSLOTS + 255) / 256, 256, 0, stream>>>(partials, merged, nparts);
    kb_boundary<<<NCLS, 256, 0, stream>>>(merged, uacc, bstar, cntab);
    kb_pass   <<<2048, 256, 0, stream>>>(pm, bstar, fine, sumab);
    kc_resolve<<<NCLS, 256, 0, stream>>>(fine, uacc, bstar, cntab, sumab, facc);
    k4_final  <<<1, 1, 0, stream>>>(facc, uacc, out);
}

// Round 5
// 137.644 us; speedup vs baseline: 9.9321x; 1.4137x over previous
//
#include <hip/hip_runtime.h>
#include <cstdint>
#include <cstddef>

#define B_ 8
#define C_ 32
#define W_ 32
#define H_ 32
#define A_ 6
#define NCLS 14
#define M_ 64
#define HARD_NUM 256
#define LAM_HNM 0.2f
#define LAM_NOOBJ 0.001f

#define NCH 17
#define NPOS (B_*C_*W_*H_*A_)
#define TOTAL (NPOS*NCH)          // 26,738,688 floats

#define ABITS 11
#define NBIN_C (1<<ABITS)         // 2048 coarse bins
#define KSHIFT (32-ABITS)         // 21
#define HSLOTS2 (NBIN_C*8)        // 16384 u32 slots (8 u16-pairs per bin)
#define SUBBITS 11
#define NBIN_F (1<<SUBBITS)       // 2048 fine sub-bins

// ws layout
#define OFF_FACC   0              // float[16]: 0=cl_pos 1=cl_neg 2=reg 3=regu 4=hn_sum
#define OFF_UACC   64             // u32[16]:  0=pos_count, 1..14=per-class hn counts
#define OFF_BSTAR  128            // i32[16]
#define OFF_CNTAB  192            // u32[16]
#define OFF_SUMAB  256            // f32[16]
#define OFF_MERGED 4096           // u32[NBIN_C*14] = 114688 B
#define OFF_FINE   (4096+114688)  // u64[NCLS*NBIN_F] = 229376 B
#define OFF_PART   (OFF_FINE+229376)
#define FIXED_BYTES OFF_PART
#define PART_STRIDE (HSLOTS2*4)   // 65536 B per partial

__device__ __forceinline__ float sp(float x) {
    return fmaxf(x, 0.0f) + log1pf(__expf(-fabsf(x)));
}

__device__ __forceinline__ unsigned fkey(float x) {
    unsigned u = __float_as_uint(x);
    return (u & 0x80000000u) ? ~u : (u | 0x80000000u);
}

// ---------------- pass A: coarse per-channel LDS count histogram -------------
// pairs 0..6 = classes (2 per u32, u16 halves); pair 7 = reg channels
// (ch0,ch2 -> lo half, ch1 -> hi half)
__global__ __launch_bounds__(1024) void ka_coarse(const float* __restrict__ pm,
                                                  unsigned* __restrict__ partials) {
    __shared__ unsigned hist[HSLOTS2];
    for (int i = threadIdx.x; i < HSLOTS2; i += blockDim.x) hist[i] = 0;
    __syncthreads();
    int tid = blockIdx.x * blockDim.x + threadIdx.x;
    int nth = gridDim.x * blockDim.x;
    for (int i = tid; i < TOTAL / 4; i += nth) {
        float4 v = reinterpret_cast<const float4*>(pm)[i];
        float vv[4] = {v.x, v.y, v.z, v.w};
        int ch = (i * 4) % NCH;
#pragma unroll
        for (int j = 0; j < 4; ++j) {
            unsigned bin = fkey(vv[j]) >> KSHIFT;
            int cm3 = ch - 3;
            int pair = (cm3 >= 0) ? (cm3 >> 1) : 7;
            unsigned hi = (cm3 >= 0) ? (unsigned)(cm3 & 1) : (unsigned)(ch == 1);
            unsigned incr = hi ? 0x10000u : 1u;
            atomicAdd(&hist[bin * 8 + pair], incr);
            ch = (ch == NCH - 1) ? 0 : ch + 1;
        }
    }
    __syncthreads();
    unsigned* dst = partials + (size_t)blockIdx.x * HSLOTS2;
    for (int i = threadIdx.x; i < HSLOTS2; i += blockDim.x) dst[i] = hist[i];
}

// ---------------- reduce partials -> merged class hist + regu softplus sum ---
__global__ void kr_reduce(const unsigned* __restrict__ partials,
                          unsigned* __restrict__ merged,
                          float* __restrict__ facc, int nparts) {
    int slot = blockIdx.x * blockDim.x + threadIdx.x;
    int p0 = (nparts * blockIdx.y) / gridDim.y;
    int p1 = (nparts * (blockIdx.y + 1)) / gridDim.y;
    unsigned a0 = 0, a1 = 0;
    for (int p = p0; p < p1; ++p) {
        unsigned v = partials[(size_t)p * HSLOTS2 + slot];
        a0 += v & 0xFFFFu;
        a1 += v >> 16;
    }
    int bin = slot >> 3, pair = slot & 7;
    if (pair < 7) {
        if (a0) atomicAdd(&merged[bin * 14 + 2 * pair], a0);
        if (a1) atomicAdd(&merged[bin * 14 + 2 * pair + 1], a1);
    }
    // softplus(rep) * count  (all 17 channels contribute to regu sum).
    // GUARD zero-count bins: their representative may decode to Inf/NaN
    // (exponent 0xFF) and 0*Inf = NaN would poison the whole reduction.
    unsigned cnt = a0 + a1;
    float contrib = 0.0f;
    if (cnt > 0) {
        unsigned kmid = ((unsigned)bin << KSHIFT) | (1u << (KSHIFT - 1));
        unsigned u = (kmid & 0x80000000u) ? (kmid & 0x7FFFFFFFu) : ~kmid;
        contrib = (float)cnt * sp(__uint_as_float(u));
    }
    for (int off = 32; off; off >>= 1) contrib += __shfl_down(contrib, off, 64);
    __shared__ float wsum[4];
    int lane = threadIdx.x & 63, wid = threadIdx.x >> 6;
    if (lane == 0) wsum[wid] = contrib;
    __syncthreads();
    if (threadIdx.x == 0) {
        float s = 0.0f;
        int nw = blockDim.x >> 6;
        for (int w = 0; w < nw; ++w) s += wsum[w];
        atomicAdd(&facc[3], s);
    }
}

// ---------------- proposals: pos losses + hn counts --------------------------
__global__ void k2_props(const float* __restrict__ pm,
                         const int* __restrict__ pidx,
                         const float* __restrict__ preg,
                         float* __restrict__ facc,
                         unsigned* __restrict__ uacc) {
    int t = blockIdx.x * blockDim.x + threadIdx.x;
    if (t >= B_ * A_ * M_) return;
    int b = t / (A_ * M_);
    int a = (t / M_) % A_;
    const int* q = pidx + (size_t)t * 4;
    int c = q[0], w = q[1], h = q[2], lab = q[3];
    if (lab == -100) return;
    if (lab < 0) {
        atomicAdd(&uacc[1 + (-1 - lab)], 1u);
        return;
    }
    atomicAdd(&uacc[0], 1u);
    const float* v = pm + (size_t)((((b * C_ + c) * W_ + w) * H_ + h) * A_ + a) * NCH;
    float clp = 0.0f, cln = 0.0f;
#pragma unroll
    for (int j = 0; j < NCLS; ++j) {
        float lg = v[3 + j];
        if (j == lab) clp = sp(-lg);
        else          cln += sp(lg);
    }
    float rg = 0.0f;
    const float* pr = preg + (size_t)t * 3;
#pragma unroll
    for (int j = 0; j < 3; ++j) {
        float d = tanhf(v[j]) - pr[j];
        float ad = fabsf(d);
        rg += (ad < 1.0f) ? 0.5f * d * d : ad - 0.5f;
    }
    atomicAdd(&facc[0], clp);
    atomicAdd(&facc[1], cln);
    atomicAdd(&facc[2], rg);
}

// ---------------- per-class coarse boundary find -----------------------------
__global__ void kb_boundary(const unsigned* __restrict__ merged,
                            const unsigned* __restrict__ uacc,
                            int* __restrict__ bstar,
                            unsigned* __restrict__ cntab) {
    int cls = blockIdx.x, t = threadIdx.x;
    unsigned k = uacc[1 + cls] * HARD_NUM;
    if (k == 0) { if (t == 0) bstar[cls] = -2; return; }
    __shared__ unsigned ck[256];
    const int CPB = NBIN_C / 256;      // 8 bins per chunk
    unsigned lc = 0;
    for (int j = 0; j < CPB; ++j) lc += merged[(t * CPB + j) * 14 + cls];
    ck[t] = lc;
    __syncthreads();
    if (t == 0) {
        unsigned cum = 0; int sc = -1;
        for (int ch = 255; ch >= 0; --ch) {
            if (cum + ck[ch] >= k) { sc = ch; break; }
            cum += ck[ch];
        }
        if (sc < 0) { bstar[cls] = -1; cntab[cls] = cum; return; }
        for (int j = CPB - 1; j >= 0; --j) {
            int bin = sc * CPB + j;
            unsigned c = merged[bin * 14 + cls];
            if (cum + c >= k) { bstar[cls] = bin; cntab[cls] = cum; return; }
            cum += c;
        }
    }
}

// ---------------- pass B: sum above boundary + fine hist of boundary bin -----
__global__ void kb_pass(const float* __restrict__ pm,
                        const int* __restrict__ bstar,
                        unsigned long long* __restrict__ fine,
                        float* __restrict__ sumab) {
    __shared__ float csum[16];
    __shared__ int bst[16];
    int t = threadIdx.x;
    if (t < 16) { csum[t] = 0.0f; bst[t] = (t < 14) ? bstar[t] : -2; }
    __syncthreads();
    int tid = blockIdx.x * blockDim.x + t;
    int nth = gridDim.x * blockDim.x;
    for (int i = tid; i < TOTAL / 4; i += nth) {
        float4 v = reinterpret_cast<const float4*>(pm)[i];
        float vv[4] = {v.x, v.y, v.z, v.w};
        int ch = (i * 4) % NCH;
#pragma unroll
        for (int j = 0; j < 4; ++j) {
            if (ch >= 3) {
                int cls = ch - 3;
                int b = bst[cls];
                if (b != -2) {
                    float x = vv[j];
                    unsigned key = fkey(x);
                    int bin = key >> KSHIFT;
                    if (bin > b) {
                        atomicAdd(&csum[cls], sp(x));
                    } else if (bin == b) {
                        unsigned sub = (key >> (KSHIFT - SUBBITS)) & (NBIN_F - 1);
                        unsigned long long pk =
                            (1ull << 43) |
                            (unsigned long long)(sp(x) * 262144.0f + 0.5f);
                        atomicAdd(&fine[(size_t)cls * NBIN_F + sub], pk);
                    }
                }
            }
            ch = (ch == NCH - 1) ? 0 : ch + 1;
        }
    }
    __syncthreads();
    if (t < 14 && csum[t] != 0.0f) atomicAdd(&sumab[t], csum[t]);
}

// ---------------- resolve fine hist -> hn sum --------------------------------
__global__ void kc_resolve(const unsigned long long* __restrict__ fine,
                           const unsigned* __restrict__ uacc,
                           const int* __restrict__ bstar,
                           const unsigned* __restrict__ cntab,
                           const float* __restrict__ sumab,
                           float* __restrict__ facc) {
    int cls = blockIdx.x, t = threadIdx.x;
    unsigned k = uacc[1 + cls] * HARD_NUM;
    if (k == 0) return;
    int b = bstar[cls];
    if (b == -1) {
        if (t == 0) atomicAdd(&facc[4], sumab[cls]);
        return;
    }
    unsigned r = k - cntab[cls];      // >= 1 by construction
    const unsigned long long* fc = fine + (size_t)cls * NBIN_F;
    const int CPB = NBIN_F / 256;     // 8
    __shared__ unsigned ck[256];
    __shared__ float cs[256];
    unsigned lc = 0; float ls = 0.0f;
    for (int j = 0; j < CPB; ++j) {
        unsigned long long v = fc[t * CPB + j];
        lc += (unsigned)(v >> 43);
        ls += (float)(v & ((1ull << 43) - 1)) * (1.0f / 262144.0f);
    }
    ck[t] = lc; cs[t] = ls;
    __syncthreads();
    if (t == 0) {
        unsigned cum = 0; float sa = sumab[cls];
        for (int ch = 255; ch >= 0; --ch) {
            if (cum + ck[ch] >= r) {
                unsigned c2 = cum;
                for (int j = CPB - 1; j >= 0; --j) {
                    unsigned long long v = fc[ch * CPB + j];
                    unsigned c = (unsigned)(v >> 43);
                    float s = (float)(v & ((1ull << 43) - 1)) * (1.0f / 262144.0f);
                    if (c2 + c >= r) {
                        unsigned rem = r - c2;
                        if (c > 0) sa += (float)rem * (s / (float)c);
                        break;
                    }
                    c2 += c; sa += s;
                }
                break;
            }
            cum += ck[ch]; sa += cs[ch];
        }
        atomicAdd(&facc[4], sa);
    }
}

// ---------------- final combine ----------------------------------------------
__global__ void k4_final(const float* __restrict__ facc,
                         const unsigned* __restrict__ uacc,
                         float* __restrict__ out) {
    float P = fmaxf((float)uacc[0], 1.0f);
    unsigned totk = 0;
    for (int j = 0; j < NCLS; ++j) totk += uacc[1 + j];
    totk *= HARD_NUM;
    float hn = (totk > 0) ? (LAM_HNM * facc[4] / (float)totk) : 0.0f;
    out[0] = facc[0] / P
           + facc[1] / (P * (float)((NCLS - 1) * (NCLS - 1)))
           + hn
           + LAM_NOOBJ * facc[3] / (float)TOTAL
           + facc[2] / (3.0f * P);
}

extern "C" void kernel_launch(void* const* d_in, const int* in_sizes, int n_in,
                              void* d_out, int out_size, void* d_ws, size_t ws_size,
                              hipStream_t stream) {
    const float* pm   = (const float*)d_in[0];
    const int*   pidx = (const int*)d_in[1];
    const float* preg = (const float*)d_in[2];
    float* out = (float*)d_out;
    char* ws = (char*)d_ws;

    float*    facc  = (float*)(ws + OFF_FACC);
    unsigned* uacc  = (unsigned*)(ws + OFF_UACC);
    int*      bstar = (int*)(ws + OFF_BSTAR);
    unsigned* cntab = (unsigned*)(ws + OFF_CNTAB);
    float*    sumab = (float*)(ws + OFF_SUMAB);
    unsigned* merged = (unsigned*)(ws + OFF_MERGED);
    unsigned long long* fine = (unsigned long long*)(ws + OFF_FINE);
    unsigned* partials = (unsigned*)(ws + OFF_PART);

    size_t avail = (ws_size > (size_t)FIXED_BYTES)
                 ? (ws_size - FIXED_BYTES) / PART_STRIDE : 0;
    int nparts = (avail < 512) ? (int)avail : 512;
    if (nparts < 16) nparts = 16;   // u16 halves safe down to ~8 parts

    (void)hipMemsetAsync(ws, 0, FIXED_BYTES, stream);
    k2_props  <<<(B_*A_*M_ + 255) / 256, 256, 0, stream>>>(pm, pidx, preg, facc, uacc);
    ka_coarse <<<nparts, 1024, 0, stream>>>(pm, partials);
    kr_reduce <<<dim3(HSLOTS2 / 256, 8), 256, 0, stream>>>(partials, merged, facc, nparts);
    kb_boundary<<<NCLS, 256, 0, stream>>>(merged, uacc, bstar, cntab);
    kb_pass   <<<2048, 256, 0, stream>>>(pm, bstar, fine, sumab);
    kc_resolve<<<NCLS, 256, 0, stream>>>(fine, uacc, bstar, cntab, sumab, facc);
    k4_final  <<<1, 1, 0, stream>>>(facc, uacc, out);
}

// Round 6
// 132.729 us; speedup vs baseline: 10.2999x; 1.0370x over previous
//
#include <hip/hip_runtime.h>
#include <cstdint>
#include <cstddef>

#define B_ 8
#define C_ 32
#define W_ 32
#define H_ 32
#define A_ 6
#define NCLS 14
#define M_ 64
#define HARD_NUM 256
#define LAM_HNM 0.2f
#define LAM_NOOBJ 0.001f

#define NCH 17
#define NPOS (B_*C_*W_*H_*A_)
#define TOTAL (NPOS*NCH)          // 26,738,688 floats

#define ABITS 11
#define NBIN_C (1<<ABITS)         // 2048 coarse bins
#define KSHIFT (32-ABITS)         // 21
#define HSLOTS2 (NBIN_C*8)        // 16384 u32 slots (7 class-pairs + 1 pad per bin)
#define SUBBITS 11
#define NBIN_F (1<<SUBBITS)       // 2048 fine sub-bins

// ws layout
#define OFF_FACC   0              // float[16]: 0=cl_pos 1=cl_neg 2=reg 3=regu 4=hn_sum
#define OFF_UACC   64             // u32[16]:  0=pos_count, 1..14=per-class hn counts
#define OFF_BSTAR  128            // i32[16]
#define OFF_CNTAB  192            // u32[16]
#define OFF_SUMAB  256            // f32[16]
#define OFF_MERGED 4096           // u32[NBIN_C*14] = 114688 B
#define OFF_FINE   (4096+114688)  // u64[NCLS*NBIN_F] = 229376 B
#define OFF_PART   (OFF_FINE+229376)
#define FIXED_BYTES OFF_PART      // 348160 B
#define PART_STRIDE (HSLOTS2*4)   // 65536 B per partial

// fast softplus: ~9 VALU ops (v_exp_f32/v_log_f32), rel err ~1e-5 — all
// consumers are scaled sums with 3.3e-2 absolute tolerance.
__device__ __forceinline__ float spf(float x) {
    return fmaxf(x, 0.0f) + __logf(1.0f + __expf(-fabsf(x)));
}
// precise version for the tiny k2 path (3072 elements)
__device__ __forceinline__ float sp(float x) {
    return fmaxf(x, 0.0f) + log1pf(__expf(-fabsf(x)));
}

__device__ __forceinline__ unsigned fkey(float x) {
    unsigned u = __float_as_uint(x);
    return (u & 0x80000000u) ? ~u : (u | 0x80000000u);
}

// ---------------- init: zero the fixed accumulator region (no memset in graph)
__global__ void k0_init(unsigned* __restrict__ ws) {
    int i = blockIdx.x * blockDim.x + threadIdx.x;
    if (i < FIXED_BYTES / 4) ws[i] = 0u;
}

// ---------------- pass A: class-channel LDS count histogram + exact regu sum -
__global__ __launch_bounds__(1024) void ka_coarse(const float* __restrict__ pm,
                                                  unsigned* __restrict__ partials,
                                                  float* __restrict__ facc) {
    __shared__ unsigned hist[HSLOTS2];
    for (int i = threadIdx.x; i < HSLOTS2; i += blockDim.x) hist[i] = 0;
    __syncthreads();
    int tid = blockIdx.x * blockDim.x + threadIdx.x;
    int nth = gridDim.x * blockDim.x;
    float racc = 0.0f;
    for (int i = tid; i < TOTAL / 4; i += nth) {
        float4 v = reinterpret_cast<const float4*>(pm)[i];
        float vv[4] = {v.x, v.y, v.z, v.w};
        int ch = (i * 4) % NCH;
#pragma unroll
        for (int j = 0; j < 4; ++j) {
            float x = vv[j];
            racc += spf(x);                       // exact regu term, all channels
            int cm3 = ch - 3;
            if (cm3 >= 0) {                       // class channels only
                unsigned bin = fkey(x) >> KSHIFT;
                unsigned incr = (cm3 & 1) ? 0x10000u : 1u;
                atomicAdd(&hist[bin * 8 + (cm3 >> 1)], incr);
            }
            ch = (ch == NCH - 1) ? 0 : ch + 1;
        }
    }
    __syncthreads();
    unsigned* dst = partials + (size_t)blockIdx.x * HSLOTS2;
    for (int i = threadIdx.x; i < HSLOTS2; i += blockDim.x) dst[i] = hist[i];
    for (int off = 32; off; off >>= 1) racc += __shfl_down(racc, off, 64);
    __shared__ float wsum[16];
    int lane = threadIdx.x & 63, wid = threadIdx.x >> 6;
    if (lane == 0) wsum[wid] = racc;
    __syncthreads();
    if (threadIdx.x == 0) {
        float s = 0.0f;
        int nw = blockDim.x >> 6;
        for (int w = 0; w < nw; ++w) s += wsum[w];
        atomicAdd(&facc[3], s);
    }
}

// ---------------- reduce partials -> merged class hist -----------------------
__global__ void kr_reduce(const unsigned* __restrict__ partials,
                          unsigned* __restrict__ merged, int nparts) {
    int slot = blockIdx.x * blockDim.x + threadIdx.x;
    int pair = slot & 7;
    if (pair >= 7) return;
    int p0 = (nparts * blockIdx.y) / gridDim.y;
    int p1 = (nparts * (blockIdx.y + 1)) / gridDim.y;
    unsigned a0 = 0, a1 = 0;
    for (int p = p0; p < p1; ++p) {
        unsigned v = partials[(size_t)p * HSLOTS2 + slot];
        a0 += v & 0xFFFFu;
        a1 += v >> 16;
    }
    int bin = slot >> 3;
    if (a0) atomicAdd(&merged[bin * 14 + 2 * pair], a0);
    if (a1) atomicAdd(&merged[bin * 14 + 2 * pair + 1], a1);
}

// ---------------- proposals: pos losses + hn counts --------------------------
__global__ void k2_props(const float* __restrict__ pm,
                         const int* __restrict__ pidx,
                         const float* __restrict__ preg,
                         float* __restrict__ facc,
                         unsigned* __restrict__ uacc) {
    int t = blockIdx.x * blockDim.x + threadIdx.x;
    if (t >= B_ * A_ * M_) return;
    int b = t / (A_ * M_);
    int a = (t / M_) % A_;
    const int* q = pidx + (size_t)t * 4;
    int c = q[0], w = q[1], h = q[2], lab = q[3];
    if (lab == -100) return;
    if (lab < 0) {
        atomicAdd(&uacc[1 + (-1 - lab)], 1u);
        return;
    }
    atomicAdd(&uacc[0], 1u);
    const float* v = pm + (size_t)((((b * C_ + c) * W_ + w) * H_ + h) * A_ + a) * NCH;
    float clp = 0.0f, cln = 0.0f;
#pragma unroll
    for (int j = 0; j < NCLS; ++j) {
        float lg = v[3 + j];
        if (j == lab) clp = sp(-lg);
        else          cln += sp(lg);
    }
    float rg = 0.0f;
    const float* pr = preg + (size_t)t * 3;
#pragma unroll
    for (int j = 0; j < 3; ++j) {
        float d = tanhf(v[j]) - pr[j];
        float ad = fabsf(d);
        rg += (ad < 1.0f) ? 0.5f * d * d : ad - 0.5f;
    }
    atomicAdd(&facc[0], clp);
    atomicAdd(&facc[1], cln);
    atomicAdd(&facc[2], rg);
}

// ---------------- per-class coarse boundary find -----------------------------
__global__ void kb_boundary(const unsigned* __restrict__ merged,
                            const unsigned* __restrict__ uacc,
                            int* __restrict__ bstar,
                            unsigned* __restrict__ cntab) {
    int cls = blockIdx.x, t = threadIdx.x;
    unsigned k = uacc[1 + cls] * HARD_NUM;
    if (k == 0) { if (t == 0) bstar[cls] = -2; return; }
    __shared__ unsigned ck[256];
    const int CPB = NBIN_C / 256;      // 8 bins per chunk
    unsigned lc = 0;
    for (int j = 0; j < CPB; ++j) lc += merged[(t * CPB + j) * 14 + cls];
    ck[t] = lc;
    __syncthreads();
    if (t == 0) {
        unsigned cum = 0; int sc = -1;
        for (int ch = 255; ch >= 0; --ch) {
            if (cum + ck[ch] >= k) { sc = ch; break; }
            cum += ck[ch];
        }
        if (sc < 0) { bstar[cls] = -1; cntab[cls] = cum; return; }
        for (int j = CPB - 1; j >= 0; --j) {
            int bin = sc * CPB + j;
            unsigned c = merged[bin * 14 + cls];
            if (cum + c >= k) { bstar[cls] = bin; cntab[cls] = cum; return; }
            cum += c;
        }
    }
}

// ---------------- pass B: sum above boundary + fine hist of boundary bin -----
__global__ void kb_pass(const float* __restrict__ pm,
                        const int* __restrict__ bstar,
                        unsigned long long* __restrict__ fine,
                        float* __restrict__ sumab) {
    __shared__ float csum[16];
    __shared__ int bst[16];
    int t = threadIdx.x;
    if (t < 16) { csum[t] = 0.0f; bst[t] = (t < 14) ? bstar[t] : -2; }
    __syncthreads();
    int tid = blockIdx.x * blockDim.x + t;
    int nth = gridDim.x * blockDim.x;
    for (int i = tid; i < TOTAL / 4; i += nth) {
        float4 v = reinterpret_cast<const float4*>(pm)[i];
        float vv[4] = {v.x, v.y, v.z, v.w};
        int ch = (i * 4) % NCH;
#pragma unroll
        for (int j = 0; j < 4; ++j) {
            if (ch >= 3) {
                int cls = ch - 3;
                int b = bst[cls];
                if (b != -2) {
                    float x = vv[j];
                    unsigned key = fkey(x);
                    int bin = key >> KSHIFT;
                    if (bin > b) {
                        atomicAdd(&csum[cls], spf(x));
                    } else if (bin == b) {
                        unsigned sub = (key >> (KSHIFT - SUBBITS)) & (NBIN_F - 1);
                        unsigned long long pk =
                            (1ull << 43) |
                            (unsigned long long)(spf(x) * 262144.0f + 0.5f);
                        atomicAdd(&fine[(size_t)cls * NBIN_F + sub], pk);
                    }
                }
            }
            ch = (ch == NCH - 1) ? 0 : ch + 1;
        }
    }
    __syncthreads();
    if (t < 14 && csum[t] != 0.0f) atomicAdd(&sumab[t], csum[t]);
}

// ---------------- resolve fine hist -> hn sum --------------------------------
__global__ void kc_resolve(const unsigned long long* __restrict__ fine,
                           const unsigned* __restrict__ uacc,
                           const int* __restrict__ bstar,
                           const unsigned* __restrict__ cntab,
                           const float* __restrict__ sumab,
                           float* __restrict__ facc) {
    int cls = blockIdx.x, t = threadIdx.x;
    unsigned k = uacc[1 + cls] * HARD_NUM;
    if (k == 0) return;
    int b = bstar[cls];
    if (b == -1) {
        if (t == 0) atomicAdd(&facc[4], sumab[cls]);
        return;
    }
    unsigned r = k - cntab[cls];      // >= 1 by construction
    const unsigned long long* fc = fine + (size_t)cls * NBIN_F;
    const int CPB = NBIN_F / 256;     // 8
    __shared__ unsigned ck[256];
    __shared__ float cs[256];
    unsigned lc = 0; float ls = 0.0f;
    for (int j = 0; j < CPB; ++j) {
        unsigned long long v = fc[t * CPB + j];
        lc += (unsigned)(v >> 43);
        ls += (float)(v & ((1ull << 43) - 1)) * (1.0f / 262144.0f);
    }
    ck[t] = lc; cs[t] = ls;
    __syncthreads();
    if (t == 0) {
        unsigned cum = 0; float sa = sumab[cls];
        for (int ch = 255; ch >= 0; --ch) {
            if (cum + ck[ch] >= r) {
                unsigned c2 = cum;
                for (int j = CPB - 1; j >= 0; --j) {
                    unsigned long long v = fc[ch * CPB + j];
                    unsigned c = (unsigned)(v >> 43);
                    float s = (float)(v & ((1ull << 43) - 1)) * (1.0f / 262144.0f);
                    if (c2 + c >= r) {
                        unsigned rem = r - c2;
                        if (c > 0) sa += (float)rem * (s / (float)c);
                        break;
                    }
                    c2 += c; sa += s;
                }
                break;
            }
            cum += ck[ch]; sa += cs[ch];
        }
        atomicAdd(&facc[4], sa);
    }
}

// ---------------- final combine ----------------------------------------------
__global__ void k4_final(const float* __restrict__ facc,
                         const unsigned* __restrict__ uacc,
                         float* __restrict__ out) {
    float P = fmaxf((float)uacc[0], 1.0f);
    unsigned totk = 0;
    for (int j = 0; j < NCLS; ++j) totk += uacc[1 + j];
    totk *= HARD_NUM;
    float hn = (totk > 0) ? (LAM_HNM * facc[4] / (float)totk) : 0.0f;
    out[0] = facc[0] / P
           + facc[1] / (P * (float)((NCLS - 1) * (NCLS - 1)))
           + hn
           + LAM_NOOBJ * facc[3] / (float)TOTAL
           + facc[2] / (3.0f * P);
}

extern "C" void kernel_launch(void* const* d_in, const int* in_sizes, int n_in,
                              void* d_out, int out_size, void* d_ws, size_t ws_size,
                              hipStream_t stream) {
    const float* pm   = (const float*)d_in[0];
    const int*   pidx = (const int*)d_in[1];
    const float* preg = (const float*)d_in[2];
    float* out = (float*)d_out;
    char* ws = (char*)d_ws;

    float*    facc  = (float*)(ws + OFF_FACC);
    unsigned* uacc  = (unsigned*)(ws + OFF_UACC);
    int*      bstar = (int*)(ws + OFF_BSTAR);
    unsigned* cntab = (unsigned*)(ws + OFF_CNTAB);
    float*    sumab = (float*)(ws + OFF_SUMAB);
    unsigned* merged = (unsigned*)(ws + OFF_MERGED);
    unsigned long long* fine = (unsigned long long*)(ws + OFF_FINE);
    unsigned* partials = (unsigned*)(ws + OFF_PART);

    size_t avail = (ws_size > (size_t)FIXED_BYTES)
                 ? (ws_size - FIXED_BYTES) / PART_STRIDE : 0;
    int nparts = (avail < 512) ? (int)avail : 512;
    if (nparts < 16) nparts = 16;

    k0_init   <<<(FIXED_BYTES / 4 + 1023) / 1024, 1024, 0, stream>>>((unsigned*)ws);
    k2_props  <<<(B_*A_*M_ + 255) / 256, 256, 0, stream>>>(pm, pidx, preg, facc, uacc);
    ka_coarse <<<nparts, 1024, 0, stream>>>(pm, partials, facc);
    kr_reduce <<<dim3(HSLOTS2 / 256, 8), 256, 0, stream>>>(partials, merged, nparts);
    kb_boundary<<<NCLS, 256, 0, stream>>>(merged, uacc, bstar, cntab);
    kb_pass   <<<2048, 256, 0, stream>>>(pm, bstar, fine, sumab);
    kc_resolve<<<NCLS, 256, 0, stream>>>(fine, uacc, bstar, cntab, sumab, facc);
    k4_final  <<<1, 1, 0, stream>>>(facc, uacc, out);
}